// Round 7
// baseline (376.283 us; speedup 1.0000x reference)
//
#include <hip/hip_runtime.h>

typedef unsigned short u16;
typedef unsigned int u32;
typedef unsigned long long u64;
typedef __attribute__((ext_vector_type(8))) short short8;
typedef __attribute__((ext_vector_type(4))) float f32x4;
typedef __attribute__((ext_vector_type(4))) u32 u32x4;

#define NB 16
#define SL 512
#define HS 1024
#define NHEAD 16
#define HD 64
#define NTOKC (16L * 512 * 1024)   // NB*SL*HS = 8,388,608
#define NWC   (1024L * 1024)       // HS*HS    = 1,048,576 (2^20)
#define NMC   (16L * 512 * 512)    // NB*SL*SL = 4,194,304 (2^22)

typedef const __attribute__((address_space(1))) u32* gas_t;
typedef __attribute__((address_space(3))) u32* las_t;

__device__ __forceinline__ void gld16(const u16* g, u16* l) {
  __builtin_amdgcn_global_load_lds((gas_t)g, (las_t)l, 16, 0, 0);
}

__device__ __forceinline__ u16 f2bf(float f) {
  union { float f; unsigned u; } c; c.f = f;
  unsigned r = c.u + 0x7FFFu + ((c.u >> 16) & 1u);
  return (u16)(r >> 16);
}
__device__ __forceinline__ float bf2f(u16 u) {
  union { float f; unsigned u; } c; c.u = ((unsigned)u) << 16;
  return c.f;
}
// packed RTNE f32x2 -> bf16x2 (low = a, high = b); gfx950 HW instruction
__device__ __forceinline__ u32 cvt_pk_bf16(float a, float b) {
  u32 r;
  asm("v_cvt_pk_bf16_f32 %0, %1, %2" : "=v"(r) : "v"(a), "v"(b));
  return r;
}

// ---------------- unified prep: cvt v/k/q/img + 4 weights + mask pack -----
// grid (8192, 6): y=0..3 tensors, y=4 weights (guard 4096), y=5 masks (x4 reps)
__global__ __launch_bounds__(256) void prep(
    const float* __restrict__ v, const float* __restrict__ k,
    const float* __restrict__ q, const float* __restrict__ img,
    const float* __restrict__ Wv, const float* __restrict__ Wk,
    const float* __restrict__ Wq, const float* __restrict__ Wm,
    const int* __restrict__ absm, const int* __restrict__ mask,
    u16* __restrict__ ovk, u16* __restrict__ xq, u16* __restrict__ pb,
    u16* __restrict__ w4, u64* __restrict__ bits) {
  const int y = blockIdx.y;
  const long bx = blockIdx.x;
  if (y < 4) {
    const float* in = y == 0 ? v : y == 1 ? k : y == 2 ? q : img;
    u16* out = y == 0 ? ovk : y == 1 ? ovk + NTOKC : y == 2 ? xq : pb;
    long i = (bx * 256 + threadIdx.x) * 4;
    float4 f = *(const float4*)(in + i);
    uint2 u;
    u.x = (unsigned)f2bf(f.x) | ((unsigned)f2bf(f.y) << 16);
    u.y = (unsigned)f2bf(f.z) | ((unsigned)f2bf(f.w) << 16);
    *(uint2*)(out + i) = u;
  } else if (y == 4) {
    if (bx >= 4096) return;
    long i = bx * 1024 + threadIdx.x * 4;     // over 4*NW concatenated
    int j = (int)(i >> 20);
    const float* in = j == 0 ? Wv : j == 1 ? Wk : j == 2 ? Wq : Wm;
    long off = i & (NWC - 1);
    float4 f = *(const float4*)(in + off);
    uint2 u;
    u.x = (unsigned)f2bf(f.x) | ((unsigned)f2bf(f.y) << 16);
    u.y = (unsigned)f2bf(f.z) | ((unsigned)f2bf(f.w) << 16);
    *(uint2*)(w4 + i) = u;
  } else {
#pragma unroll
    for (int rep = 0; rep < 4; ++rep) {
      long i = (bx * 4 + rep) * 256 + threadIdx.x;  // over 2*NM
      const int* m = (i >= NMC) ? mask : absm;
      long off = i & (NMC - 1);
      u64 bset = __ballot(m[off] != 0);
      if ((threadIdx.x & 63) == 0) bits[i >> 6] = bset;
    }
  }
}

// ------- triple-batched projection GEMM: {v,k,q} @ {Wv,Wk,Wq}^T ----------
// 128x128 tile, BK=64, grid (192,8)=1536 blocks. gld16 + xor-cb LDS.
__global__ __launch_bounds__(256) void gemm_p3(const u16* __restrict__ Avk,
                                               const u16* __restrict__ Aq,
                                               const u16* __restrict__ W4,
                                               u16* __restrict__ Cb) {
  __shared__ u16 As[128 * 64];
  __shared__ u16 Bs[128 * 64];
  const int tid = threadIdx.x;
  const int wave = tid >> 6, lane = tid & 63;
  const int quad = lane >> 4, l16 = lane & 15;
  const int l7 = l16 & 7;
  const int sel = blockIdx.x >> 6;
  const int row0 = (blockIdx.x & 63) * 128, col0 = blockIdx.y * 128;
  const int wm = (wave >> 1) * 64, wn = (wave & 1) * 64;
  const int lrow = lane >> 3;
  const int scb = (lane & 7) ^ lrow;
  const int K = HS, N = HS;

  const u16* A = (sel == 2) ? Aq : Avk + (long)sel * NTOKC;
  const u16* W = W4 + (long)sel * NWC;
  u16* C = Cb + (long)sel * NTOKC;

  f32x4 acc[4][4];
#pragma unroll
  for (int mt = 0; mt < 4; ++mt)
#pragma unroll
    for (int nt = 0; nt < 4; ++nt) acc[mt][nt] = (f32x4){0.f, 0.f, 0.f, 0.f};

  const u16* Ab = A + (long)row0 * K;
  const u16* Wb = W + (long)col0 * K;

  for (int k0 = 0; k0 < K; k0 += 64) {
    __syncthreads();
#pragma unroll
    for (int it = 0; it < 4; ++it) {
      int seg = wave * 4 + it;
      int r = seg * 8 + lrow;
      gld16(Ab + (long)r * K + k0 + scb * 8, As + seg * 512);
      gld16(Wb + (long)r * K + k0 + scb * 8, Bs + seg * 512);
    }
    __syncthreads();
#pragma unroll
    for (int kt = 0; kt < 2; ++kt) {
      short8 af[4], bw[4];
#pragma unroll
      for (int mt = 0; mt < 4; ++mt)
        af[mt] = *(const short8*)(As + (wm + mt * 16 + l16) * 64 +
                                  (((kt * 4 + quad) ^ l7) * 8));
#pragma unroll
      for (int nt = 0; nt < 4; ++nt)
        bw[nt] = *(const short8*)(Bs + (wn + nt * 16 + l16) * 64 +
                                  (((kt * 4 + quad) ^ l7) * 8));
#pragma unroll
      for (int mt = 0; mt < 4; ++mt)
#pragma unroll
        for (int nt = 0; nt < 4; ++nt)
          acc[mt][nt] = __builtin_amdgcn_mfma_f32_16x16x32_bf16(
              af[mt], bw[nt], acc[mt][nt], 0, 0, 0);
    }
  }
#pragma unroll
  for (int mt = 0; mt < 4; ++mt)
#pragma unroll
    for (int nt = 0; nt < 4; ++nt)
#pragma unroll
      for (int i = 0; i < 4; ++i) {
        long r = row0 + wm + mt * 16 + quad * 4 + i;
        long c = col0 + wn + nt * 16 + l16;
        C[r * N + c] = f2bf(acc[mt][nt][i]);
      }
}

// ---------------- final GEMM: out[f32] = att @ Wm^T ----------------------
// 128x128 tile clone of gemm_p3, f32 epilogue. grid (64, 8).
__global__ __launch_bounds__(256) void gemm_f(const u16* __restrict__ A,
                                              const u16* __restrict__ W,
                                              float* __restrict__ C) {
  __shared__ u16 As[128 * 64];
  __shared__ u16 Bs[128 * 64];
  const int tid = threadIdx.x;
  const int wave = tid >> 6, lane = tid & 63;
  const int quad = lane >> 4, l16 = lane & 15;
  const int l7 = l16 & 7;
  const int row0 = blockIdx.x * 128, col0 = blockIdx.y * 128;
  const int wm = (wave >> 1) * 64, wn = (wave & 1) * 64;
  const int lrow = lane >> 3;
  const int scb = (lane & 7) ^ lrow;
  const int K = HS, N = HS;

  f32x4 acc[4][4];
#pragma unroll
  for (int mt = 0; mt < 4; ++mt)
#pragma unroll
    for (int nt = 0; nt < 4; ++nt) acc[mt][nt] = (f32x4){0.f, 0.f, 0.f, 0.f};

  const u16* Ab = A + (long)row0 * K;
  const u16* Wb = W + (long)col0 * K;

  for (int k0 = 0; k0 < K; k0 += 64) {
    __syncthreads();
#pragma unroll
    for (int it = 0; it < 4; ++it) {
      int seg = wave * 4 + it;
      int r = seg * 8 + lrow;
      gld16(Ab + (long)r * K + k0 + scb * 8, As + seg * 512);
      gld16(Wb + (long)r * K + k0 + scb * 8, Bs + seg * 512);
    }
    __syncthreads();
#pragma unroll
    for (int kt = 0; kt < 2; ++kt) {
      short8 af[4], bw[4];
#pragma unroll
      for (int mt = 0; mt < 4; ++mt)
        af[mt] = *(const short8*)(As + (wm + mt * 16 + l16) * 64 +
                                  (((kt * 4 + quad) ^ l7) * 8));
#pragma unroll
      for (int nt = 0; nt < 4; ++nt)
        bw[nt] = *(const short8*)(Bs + (wn + nt * 16 + l16) * 64 +
                                  (((kt * 4 + quad) ^ l7) * 8));
#pragma unroll
      for (int mt = 0; mt < 4; ++mt)
#pragma unroll
        for (int nt = 0; nt < 4; ++nt)
          acc[mt][nt] = __builtin_amdgcn_mfma_f32_16x16x32_bf16(
              af[mt], bw[nt], acc[mt][nt], 0, 0, 0);
    }
  }
#pragma unroll
  for (int mt = 0; mt < 4; ++mt)
#pragma unroll
    for (int nt = 0; nt < 4; ++nt)
#pragma unroll
      for (int i = 0; i < 4; ++i) {
        long r = row0 + wm + mt * 16 + quad * 4 + i;
        long c = col0 + wn + nt * 16 + l16;
        C[r * N + c] = acc[mt][nt][i];
      }
}

// ------- one attention stage: 256 q-rows/block, 2 passes/wave ------------
// Double-buffered K/V, 1 barrier/tile. K/V fragments read from LDS per
// pass (NOT reg-cached: keeps total VGPR < 128 so 2 blocks/CU = 4 waves/
// SIMD resident -- round 6's reg-cached variant spilled at the 128 arch
// split). Masks double-buffered one tile ahead. Swapped QK^T +
// in-register P transpose (double shuffle).
template <bool SAME>
__device__ __forceinline__ void attn_stage(
    const u16* __restrict__ Kb, const u16* __restrict__ Vb,
    const u64* __restrict__ Mb, int qrow0, short8 qf[2][2], float l_p[2],
    f32x4 o[2][4], u16 (*Ks)[72], u16 (*Vs)[72],
    int quad, int l16, int sr, int sds, int vcol) {
  uint4 kp = *(const uint4*)(Kb + (long)sr * HS + sds);
  uint4 vp;
  if (!SAME) vp = *(const uint4*)(Vb + (long)sr * HS + sds);
  u64 mcur[2], mnxt[2];
#pragma unroll
  for (int p = 0; p < 2; ++p) mcur[p] = Mb[(long)(qrow0 + p * 128) * 8];
  {
    *(uint4*)&Ks[sr][sds] = kp;
    union { uint4 q; u16 e[8]; } tv;
    tv.q = SAME ? kp : vp;
#pragma unroll
    for (int j = 0; j < 8; ++j) Vs[sds + j][vcol] = tv.e[j];
  }
  __syncthreads();
  for (int t = 0; t < 8; ++t) {
    const int cur = t & 1;
    if (t < 7) {  // prefetch next tile: K/V/masks (hidden under 2 passes)
      kp = *(const uint4*)(Kb + (long)((t + 1) * 64 + sr) * HS + sds);
      if (!SAME)
        vp = *(const uint4*)(Vb + (long)((t + 1) * 64 + sr) * HS + sds);
#pragma unroll
      for (int p = 0; p < 2; ++p)
        mnxt[p] = Mb[(long)(qrow0 + p * 128) * 8 + t + 1];
    }
    u16(*Kc)[72] = Ks + cur * 64;
    u16(*Vc)[72] = Vs + cur * 64;
#pragma unroll
    for (int p = 0; p < 2; ++p) {
      // S^T = K Qm^T (swapped operands)
      f32x4 s[4];
#pragma unroll
      for (int nt = 0; nt < 4; ++nt) s[nt] = (f32x4){0.f, 0.f, 0.f, 0.f};
#pragma unroll
      for (int kt = 0; kt < 2; ++kt)
#pragma unroll
        for (int nt = 0; nt < 4; ++nt) {
          short8 ak = *(const short8*)&Kc[nt * 16 + l16][kt * 32 + quad * 8];
          s[nt] = __builtin_amdgcn_mfma_f32_16x16x32_bf16(ak, qf[p][kt],
                                                          s[nt], 0, 0, 0);
        }
      // mask + exp + packed bf16 pairs; l partial (lane's q-row = l16)
      const u64 mw = mcur[p];
      u32 pk[8];
      float lp = 0.f;
#pragma unroll
      for (int nt = 0; nt < 4; ++nt) {
        const u32 mb = (u32)(mw >> (nt * 16 + quad * 4));
#pragma unroll
        for (int ih = 0; ih < 2; ++ih) {
          float p0 = (mb & (1u << (2 * ih)))
                         ? 0.f
                         : __expf(s[nt][2 * ih] * 0.125f);
          float p1 = (mb & (1u << (2 * ih + 1)))
                         ? 0.f
                         : __expf(s[nt][2 * ih + 1] * 0.125f);
          lp += p0 + p1;
          pk[nt * 2 + ih] = cvt_pk_bf16(p0, p1);
        }
      }
      l_p[p] += lp;
      // in-register transpose P^T -> P A-frags (double shuffle), O += P V
#pragma unroll
      for (int kt = 0; kt < 2; ++kt) {
        u32x4 av;
#pragma unroll
        for (int j2 = 0; j2 < 4; ++j2) {
          int src = ((quad & 1) * 2 + (j2 >> 1)) * 16 + l16;
          u32 vlo = (u32)__shfl((int)pk[(2 * kt) * 2 + (j2 & 1)], src, 64);
          u32 vhi = (u32)__shfl((int)pk[(2 * kt + 1) * 2 + (j2 & 1)], src, 64);
          av[j2] = (quad & 2) ? vhi : vlo;
        }
        union { u32x4 u; short8 s8; } cv;
        cv.u = av;
#pragma unroll
        for (int nt = 0; nt < 4; ++nt) {
          short8 bv = *(const short8*)&Vc[nt * 16 + l16]
                                        [(kt * 32 + quad * 8) ^ ((nt & 3) << 4)];
          o[p][nt] = __builtin_amdgcn_mfma_f32_16x16x32_bf16(
              cv.s8, bv, o[p][nt], 0, 0, 0);
        }
      }
    }
    // write tile t+1 into the other buffer; single barrier per tile
    if (t < 7) {
      u16(*Kn)[72] = Ks + (cur ^ 1) * 64;
      u16(*Vn)[72] = Vs + (cur ^ 1) * 64;
      *(uint4*)&Kn[sr][sds] = kp;
      union { uint4 q; u16 e[8]; } tv;
      tv.q = SAME ? kp : vp;
#pragma unroll
      for (int j = 0; j < 8; ++j) Vn[sds + j][vcol] = tv.e[j];
      mcur[0] = mnxt[0];
      mcur[1] = mnxt[1];
      __syncthreads();
    }
  }
}

// ---------------- fused modulate+main attention ----------------
// One block = (b, h, 256 q-rows): 2 passes x 8 waves x 16 rows. Grid
// (2,16,16) = 512 blocks = 2/CU. LDS 36.9 KB (2 blocks = 73.7KB <= 160).
// __launch_bounds__(512,4): VGPR cap 128 -> 4 waves/SIMD. Demand ~118
// (no frag caching). Tripwire: VGPR=128 + WRITE_SIZE>17MB => spilled.
__global__ __launch_bounds__(512, 4) void attn_fused(
    const u16* __restrict__ Qp, const u16* __restrict__ Pbp,
    const u16* __restrict__ Kp, const u16* __restrict__ Vp,
    const u64* __restrict__ B0, const u64* __restrict__ B1,
    u16* __restrict__ Op) {
  __shared__ u16 Ks[128][72];  // [0:64) buf0, [64:128) buf1
  __shared__ u16 Vs[128][72];
  const int tid = threadIdx.x;
  const int wave = tid >> 6, lane = tid & 63;
  const int quad = lane >> 4, l16 = lane & 15;
  const int qt = blockIdx.x, h = blockIdx.y, b = blockIdx.z;
  const int q0 = qt * 256;
  const long bs = (long)SL * HS;
  const u16* Qb = Qp + (long)b * bs + h * HD;
  const u16* Pb = Pbp + (long)b * bs + h * HD;
  const u16* Kb = Kp + (long)b * bs + h * HD;
  const u16* Vb = Vp + (long)b * bs + h * HD;
  const u64* M0 = B0 + (long)b * SL * 8;
  const u64* M1 = B1 + (long)b * SL * 8;
  const int sr = tid >> 3, sds = (tid & 7) * 8;
  const int vcol = sr ^ (((sds >> 4) & 3) << 4);
  const int qrow0 = q0 + wave * 16 + l16;  // pass p -> q-row qrow0 + p*128

  // Q A-frags -> registers (2 passes)
  short8 qf[2][2];
#pragma unroll
  for (int p = 0; p < 2; ++p)
#pragma unroll
    for (int kt = 0; kt < 2; ++kt)
      qf[p][kt] = *(const short8*)(Qb + (long)(qrow0 + p * 128) * HS +
                                   kt * 32 + quad * 8);

  float l_p[2] = {0.f, 0.f};
  f32x4 o[2][4];
#pragma unroll
  for (int p = 0; p < 2; ++p)
#pragma unroll
    for (int nt = 0; nt < 4; ++nt) o[p][nt] = (f32x4){0.f, 0.f, 0.f, 0.f};

  // ---- stage 1: modulate over img_abs (K = V = pb) ----
  attn_stage<true>(Pb, Pb, M0, qrow0, qf, l_p, o, Ks, Vs, quad, l16, sr, sds,
                   vcol);

  // ---- qm = Q + O/l per pass: O (C-layout) -> LDS -> A-layout, add Q ----
  __syncthreads();  // stage-1 tile-7 frag reads done before Ks overwrite
#pragma unroll
  for (int p = 0; p < 2; ++p) {
    float rs = l_p[p];
    rs += __shfl_xor(rs, 16, 64);
    rs += __shfl_xor(rs, 32, 64);
    float inv = 1.f / rs;  // row-sum^-1 for q-row qrow0 + p*128
    float invq[4];
#pragma unroll
    for (int i = 0; i < 4; ++i) invq[i] = __shfl(inv, quad * 4 + i, 64);
#pragma unroll
    for (int i = 0; i < 4; ++i)
#pragma unroll
      for (int nt = 0; nt < 4; ++nt)
        Ks[wave * 16 + quad * 4 + i][nt * 16 + l16] =
            f2bf(o[p][nt][i] * invq[i]);
    // wave-private rows: in-order LDS + compiler lgkmcnt; no barrier
#pragma unroll
    for (int kt = 0; kt < 2; ++kt) {
      short8 t8 = *(const short8*)&Ks[wave * 16 + l16][kt * 32 + quad * 8];
#pragma unroll
      for (int j = 0; j < 8; ++j)
        qf[p][kt][j] = (short)f2bf(bf2f((u16)t8[j]) + bf2f((u16)qf[p][kt][j]));
    }
#pragma unroll
    for (int nt = 0; nt < 4; ++nt) o[p][nt] = (f32x4){0.f, 0.f, 0.f, 0.f};
    l_p[p] = 0.f;
  }
  __syncthreads();  // rebuild reads done before stage-2 prologue writes

  // ---- stage 2: main attention over kh/vh ----
  attn_stage<false>(Kb, Vb, M1, qrow0, qf, l_p, o, Ks, Vs, quad, l16, sr, sds,
                    vcol);

  // ---- epilogue ----
  u16* Ob = Op + (long)b * bs + h * HD;
#pragma unroll
  for (int p = 0; p < 2; ++p) {
    float rs = l_p[p];
    rs += __shfl_xor(rs, 16, 64);
    rs += __shfl_xor(rs, 32, 64);
    float inv = 1.f / rs;
    float invq[4];
#pragma unroll
    for (int i = 0; i < 4; ++i) invq[i] = __shfl(inv, quad * 4 + i, 64);
#pragma unroll
    for (int i = 0; i < 4; ++i) {
      int r = q0 + p * 128 + wave * 16 + quad * 4 + i;
#pragma unroll
      for (int nt = 0; nt < 4; ++nt)
        Ob[(long)r * HS + nt * 16 + l16] = f2bf(o[p][nt][i] * invq[i]);
    }
  }
}

extern "C" void kernel_launch(void* const* d_in, const int* in_sizes, int n_in,
                              void* d_out, int out_size, void* d_ws,
                              size_t ws_size, hipStream_t stream) {
  const float* v   = (const float*)d_in[0];
  const float* k   = (const float*)d_in[1];
  const float* q   = (const float*)d_in[2];
  const float* img = (const float*)d_in[3];
  const float* Wv  = (const float*)d_in[4];
  const float* Wk  = (const float*)d_in[5];
  const float* Wq  = (const float*)d_in[6];
  const float* Wm  = (const float*)d_in[7];
  const int* absm  = (const int*)d_in[8];
  const int* mask  = (const int*)d_in[9];
  float* out = (float*)d_out;

  const long NTOK = NTOKC;
  const long NW   = NWC;
  const long NM   = NMC;
  // d_out (33.5 MB) doubles as bf16 staging for v,k; consumed by gemm_p3
  // before gemm_f overwrites it.
  u16* ovk = (u16*)d_out;
  u16* ws  = (u16*)d_ws;
  u16* xq  = ws;              // q bf16 staging; att output after attn_fused
  u16* pb  = ws + 1 * NTOK;   // img_abs bf16
  u16* vh  = ws + 2 * NTOK;   // gemm_p3 C base (vh,kh,qh contiguous)
  u16* kh  = ws + 3 * NTOK;
  u16* qh  = ws + 4 * NTOK;
  u16* w4  = ws + 5 * NTOK;
  u64* bt0 = (u64*)(w4 + 4 * NW);
  u64* bt1 = bt0 + NM / 64;
  u16* att = xq;

  prep<<<dim3(8192, 6), 256, 0, stream>>>(v, k, q, img, Wv, Wk, Wq, Wm,
                                          absm, mask, ovk, xq, pb, w4, bt0);
  gemm_p3<<<dim3(192, 8), 256, 0, stream>>>(ovk, xq, w4, vh);
  attn_fused<<<dim3(SL / 256, NHEAD, NB), 512, 0, stream>>>(
      qh, pb, kh, vh, bt0, bt1, att);
  gemm_f<<<dim3(NB * SL / 128, HS / 128), 256, 0, stream>>>(att, w4 + 3 * NW,
                                                            out);
}

// Round 8
// 371.383 us; speedup vs baseline: 1.0132x; 1.0132x over previous
//
#include <hip/hip_runtime.h>

typedef unsigned short u16;
typedef unsigned int u32;
typedef unsigned long long u64;
typedef __attribute__((ext_vector_type(8))) short short8;
typedef __attribute__((ext_vector_type(4))) float f32x4;
typedef __attribute__((ext_vector_type(4))) u32 u32x4;

#define NB 16
#define SL 512
#define HS 1024
#define NHEAD 16
#define HD 64
#define NTOKC (16L * 512 * 1024)   // NB*SL*HS = 8,388,608
#define NWC   (1024L * 1024)       // HS*HS    = 1,048,576 (2^20)
#define NMC   (16L * 512 * 512)    // NB*SL*SL = 4,194,304 (2^22)

typedef const __attribute__((address_space(1))) u32* gas_t;
typedef __attribute__((address_space(3))) u32* las_t;

__device__ __forceinline__ void gld16(const u16* g, u16* l) {
  __builtin_amdgcn_global_load_lds((gas_t)g, (las_t)l, 16, 0, 0);
}

__device__ __forceinline__ u16 f2bf(float f) {
  union { float f; unsigned u; } c; c.f = f;
  unsigned r = c.u + 0x7FFFu + ((c.u >> 16) & 1u);
  return (u16)(r >> 16);
}
__device__ __forceinline__ float bf2f(u16 u) {
  union { float f; unsigned u; } c; c.u = ((unsigned)u) << 16;
  return c.f;
}
// packed RTNE f32x2 -> bf16x2 (low = a, high = b); gfx950 HW instruction
__device__ __forceinline__ u32 cvt_pk_bf16(float a, float b) {
  u32 r;
  asm("v_cvt_pk_bf16_f32 %0, %1, %2" : "=v"(r) : "v"(a), "v"(b));
  return r;
}

// ---------------- unified prep: cvt v/k/q/img + 4 weights + mask pack -----
// grid (8192, 6): y=0..3 tensors, y=4 weights (guard 4096), y=5 masks (x4 reps)
__global__ __launch_bounds__(256) void prep(
    const float* __restrict__ v, const float* __restrict__ k,
    const float* __restrict__ q, const float* __restrict__ img,
    const float* __restrict__ Wv, const float* __restrict__ Wk,
    const float* __restrict__ Wq, const float* __restrict__ Wm,
    const int* __restrict__ absm, const int* __restrict__ mask,
    u16* __restrict__ ovk, u16* __restrict__ xq, u16* __restrict__ pb,
    u16* __restrict__ w4, u64* __restrict__ bits) {
  const int y = blockIdx.y;
  const long bx = blockIdx.x;
  if (y < 4) {
    const float* in = y == 0 ? v : y == 1 ? k : y == 2 ? q : img;
    u16* out = y == 0 ? ovk : y == 1 ? ovk + NTOKC : y == 2 ? xq : pb;
    long i = (bx * 256 + threadIdx.x) * 4;
    float4 f = *(const float4*)(in + i);
    uint2 u;
    u.x = (unsigned)f2bf(f.x) | ((unsigned)f2bf(f.y) << 16);
    u.y = (unsigned)f2bf(f.z) | ((unsigned)f2bf(f.w) << 16);
    *(uint2*)(out + i) = u;
  } else if (y == 4) {
    if (bx >= 4096) return;
    long i = bx * 1024 + threadIdx.x * 4;     // over 4*NW concatenated
    int j = (int)(i >> 20);
    const float* in = j == 0 ? Wv : j == 1 ? Wk : j == 2 ? Wq : Wm;
    long off = i & (NWC - 1);
    float4 f = *(const float4*)(in + off);
    uint2 u;
    u.x = (unsigned)f2bf(f.x) | ((unsigned)f2bf(f.y) << 16);
    u.y = (unsigned)f2bf(f.z) | ((unsigned)f2bf(f.w) << 16);
    *(uint2*)(w4 + i) = u;
  } else {
#pragma unroll
    for (int rep = 0; rep < 4; ++rep) {
      long i = (bx * 4 + rep) * 256 + threadIdx.x;  // over 2*NM
      const int* m = (i >= NMC) ? mask : absm;
      long off = i & (NMC - 1);
      u64 bset = __ballot(m[off] != 0);
      if ((threadIdx.x & 63) == 0) bits[i >> 6] = bset;
    }
  }
}

// ------- triple-batched projection GEMM: {v,k,q} @ {Wv,Wk,Wq}^T ----------
// 128x128 tile, BK=64, grid (192,8)=1536 blocks. gld16 + xor-cb LDS.
__global__ __launch_bounds__(256) void gemm_p3(const u16* __restrict__ Avk,
                                               const u16* __restrict__ Aq,
                                               const u16* __restrict__ W4,
                                               u16* __restrict__ Cb) {
  __shared__ u16 As[128 * 64];
  __shared__ u16 Bs[128 * 64];
  const int tid = threadIdx.x;
  const int wave = tid >> 6, lane = tid & 63;
  const int quad = lane >> 4, l16 = lane & 15;
  const int l7 = l16 & 7;
  const int sel = blockIdx.x >> 6;
  const int row0 = (blockIdx.x & 63) * 128, col0 = blockIdx.y * 128;
  const int wm = (wave >> 1) * 64, wn = (wave & 1) * 64;
  const int lrow = lane >> 3;
  const int scb = (lane & 7) ^ lrow;
  const int K = HS, N = HS;

  const u16* A = (sel == 2) ? Aq : Avk + (long)sel * NTOKC;
  const u16* W = W4 + (long)sel * NWC;
  u16* C = Cb + (long)sel * NTOKC;

  f32x4 acc[4][4];
#pragma unroll
  for (int mt = 0; mt < 4; ++mt)
#pragma unroll
    for (int nt = 0; nt < 4; ++nt) acc[mt][nt] = (f32x4){0.f, 0.f, 0.f, 0.f};

  const u16* Ab = A + (long)row0 * K;
  const u16* Wb = W + (long)col0 * K;

  for (int k0 = 0; k0 < K; k0 += 64) {
    __syncthreads();
#pragma unroll
    for (int it = 0; it < 4; ++it) {
      int seg = wave * 4 + it;
      int r = seg * 8 + lrow;
      gld16(Ab + (long)r * K + k0 + scb * 8, As + seg * 512);
      gld16(Wb + (long)r * K + k0 + scb * 8, Bs + seg * 512);
    }
    __syncthreads();
#pragma unroll
    for (int kt = 0; kt < 2; ++kt) {
      short8 af[4], bw[4];
#pragma unroll
      for (int mt = 0; mt < 4; ++mt)
        af[mt] = *(const short8*)(As + (wm + mt * 16 + l16) * 64 +
                                  (((kt * 4 + quad) ^ l7) * 8));
#pragma unroll
      for (int nt = 0; nt < 4; ++nt)
        bw[nt] = *(const short8*)(Bs + (wn + nt * 16 + l16) * 64 +
                                  (((kt * 4 + quad) ^ l7) * 8));
#pragma unroll
      for (int mt = 0; mt < 4; ++mt)
#pragma unroll
        for (int nt = 0; nt < 4; ++nt)
          acc[mt][nt] = __builtin_amdgcn_mfma_f32_16x16x32_bf16(
              af[mt], bw[nt], acc[mt][nt], 0, 0, 0);
    }
  }
#pragma unroll
  for (int mt = 0; mt < 4; ++mt)
#pragma unroll
    for (int nt = 0; nt < 4; ++nt)
#pragma unroll
      for (int i = 0; i < 4; ++i) {
        long r = row0 + wm + mt * 16 + quad * 4 + i;
        long c = col0 + wn + nt * 16 + l16;
        C[r * N + c] = f2bf(acc[mt][nt][i]);
      }
}

// ---------------- final GEMM: out[f32] = att @ Wm^T ----------------------
// 128x128 tile clone of gemm_p3, f32 epilogue. grid (64, 8).
__global__ __launch_bounds__(256) void gemm_f(const u16* __restrict__ A,
                                              const u16* __restrict__ W,
                                              float* __restrict__ C) {
  __shared__ u16 As[128 * 64];
  __shared__ u16 Bs[128 * 64];
  const int tid = threadIdx.x;
  const int wave = tid >> 6, lane = tid & 63;
  const int quad = lane >> 4, l16 = lane & 15;
  const int l7 = l16 & 7;
  const int row0 = blockIdx.x * 128, col0 = blockIdx.y * 128;
  const int wm = (wave >> 1) * 64, wn = (wave & 1) * 64;
  const int lrow = lane >> 3;
  const int scb = (lane & 7) ^ lrow;
  const int K = HS, N = HS;

  f32x4 acc[4][4];
#pragma unroll
  for (int mt = 0; mt < 4; ++mt)
#pragma unroll
    for (int nt = 0; nt < 4; ++nt) acc[mt][nt] = (f32x4){0.f, 0.f, 0.f, 0.f};

  const u16* Ab = A + (long)row0 * K;
  const u16* Wb = W + (long)col0 * K;

  for (int k0 = 0; k0 < K; k0 += 64) {
    __syncthreads();
#pragma unroll
    for (int it = 0; it < 4; ++it) {
      int seg = wave * 4 + it;
      int r = seg * 8 + lrow;
      gld16(Ab + (long)r * K + k0 + scb * 8, As + seg * 512);
      gld16(Wb + (long)r * K + k0 + scb * 8, Bs + seg * 512);
    }
    __syncthreads();
#pragma unroll
    for (int kt = 0; kt < 2; ++kt) {
      short8 af[4], bw[4];
#pragma unroll
      for (int mt = 0; mt < 4; ++mt)
        af[mt] = *(const short8*)(As + (wm + mt * 16 + l16) * 64 +
                                  (((kt * 4 + quad) ^ l7) * 8));
#pragma unroll
      for (int nt = 0; nt < 4; ++nt)
        bw[nt] = *(const short8*)(Bs + (wn + nt * 16 + l16) * 64 +
                                  (((kt * 4 + quad) ^ l7) * 8));
#pragma unroll
      for (int mt = 0; mt < 4; ++mt)
#pragma unroll
        for (int nt = 0; nt < 4; ++nt)
          acc[mt][nt] = __builtin_amdgcn_mfma_f32_16x16x32_bf16(
              af[mt], bw[nt], acc[mt][nt], 0, 0, 0);
    }
  }
#pragma unroll
  for (int mt = 0; mt < 4; ++mt)
#pragma unroll
    for (int nt = 0; nt < 4; ++nt)
#pragma unroll
      for (int i = 0; i < 4; ++i) {
        long r = row0 + wm + mt * 16 + quad * 4 + i;
        long c = col0 + wn + nt * 16 + l16;
        C[r * N + c] = acc[mt][nt][i];
      }
}

// ------- one attention stage: 256 q-rows/block, 2 passes/wave ------------
// Double-buffered K/V, 1 barrier/tile. K/V fragments read from LDS per
// pass. Masks double-buffered one tile ahead. Swapped QK^T + in-register
// P transpose (double shuffle).
template <bool SAME>
__device__ __forceinline__ void attn_stage(
    const u16* __restrict__ Kb, const u16* __restrict__ Vb,
    const u64* __restrict__ Mb, int qrow0, short8 qf[2][2], float l_p[2],
    f32x4 o[2][4], u16 (*Ks)[72], u16 (*Vs)[72],
    int quad, int l16, int sr, int sds, int vcol) {
  uint4 kp = *(const uint4*)(Kb + (long)sr * HS + sds);
  uint4 vp;
  if (!SAME) vp = *(const uint4*)(Vb + (long)sr * HS + sds);
  u64 mcur[2], mnxt[2];
#pragma unroll
  for (int p = 0; p < 2; ++p) mcur[p] = Mb[(long)(qrow0 + p * 128) * 8];
  {
    *(uint4*)&Ks[sr][sds] = kp;
    union { uint4 q; u16 e[8]; } tv;
    tv.q = SAME ? kp : vp;
#pragma unroll
    for (int j = 0; j < 8; ++j) Vs[sds + j][vcol] = tv.e[j];
  }
  __syncthreads();
  for (int t = 0; t < 8; ++t) {
    const int cur = t & 1;
    if (t < 7) {  // prefetch next tile: K/V/masks (hidden under 2 passes)
      kp = *(const uint4*)(Kb + (long)((t + 1) * 64 + sr) * HS + sds);
      if (!SAME)
        vp = *(const uint4*)(Vb + (long)((t + 1) * 64 + sr) * HS + sds);
#pragma unroll
      for (int p = 0; p < 2; ++p)
        mnxt[p] = Mb[(long)(qrow0 + p * 128) * 8 + t + 1];
    }
    u16(*Kc)[72] = Ks + cur * 64;
    u16(*Vc)[72] = Vs + cur * 64;
#pragma unroll
    for (int p = 0; p < 2; ++p) {
      // S^T = K Qm^T (swapped operands)
      f32x4 s[4];
#pragma unroll
      for (int nt = 0; nt < 4; ++nt) s[nt] = (f32x4){0.f, 0.f, 0.f, 0.f};
#pragma unroll
      for (int kt = 0; kt < 2; ++kt)
#pragma unroll
        for (int nt = 0; nt < 4; ++nt) {
          short8 ak = *(const short8*)&Kc[nt * 16 + l16][kt * 32 + quad * 8];
          s[nt] = __builtin_amdgcn_mfma_f32_16x16x32_bf16(ak, qf[p][kt],
                                                          s[nt], 0, 0, 0);
        }
      // mask + exp + packed bf16 pairs; l partial (lane's q-row = l16)
      const u64 mw = mcur[p];
      u32 pk[8];
      float lp = 0.f;
#pragma unroll
      for (int nt = 0; nt < 4; ++nt) {
        const u32 mb = (u32)(mw >> (nt * 16 + quad * 4));
#pragma unroll
        for (int ih = 0; ih < 2; ++ih) {
          float p0 = (mb & (1u << (2 * ih)))
                         ? 0.f
                         : __expf(s[nt][2 * ih] * 0.125f);
          float p1 = (mb & (1u << (2 * ih + 1)))
                         ? 0.f
                         : __expf(s[nt][2 * ih + 1] * 0.125f);
          lp += p0 + p1;
          pk[nt * 2 + ih] = cvt_pk_bf16(p0, p1);
        }
      }
      l_p[p] += lp;
      // in-register transpose P^T -> P A-frags (double shuffle), O += P V
#pragma unroll
      for (int kt = 0; kt < 2; ++kt) {
        u32x4 av;
#pragma unroll
        for (int j2 = 0; j2 < 4; ++j2) {
          int src = ((quad & 1) * 2 + (j2 >> 1)) * 16 + l16;
          u32 vlo = (u32)__shfl((int)pk[(2 * kt) * 2 + (j2 & 1)], src, 64);
          u32 vhi = (u32)__shfl((int)pk[(2 * kt + 1) * 2 + (j2 & 1)], src, 64);
          av[j2] = (quad & 2) ? vhi : vlo;
        }
        union { u32x4 u; short8 s8; } cv;
        cv.u = av;
#pragma unroll
        for (int nt = 0; nt < 4; ++nt) {
          short8 bv = *(const short8*)&Vc[nt * 16 + l16]
                                        [(kt * 32 + quad * 8) ^ ((nt & 3) << 4)];
          o[p][nt] = __builtin_amdgcn_mfma_f32_16x16x32_bf16(
              cv.s8, bv, o[p][nt], 0, 0, 0);
        }
      }
    }
    // write tile t+1 into the other buffer; single barrier per tile
    if (t < 7) {
      u16(*Kn)[72] = Ks + (cur ^ 1) * 64;
      u16(*Vn)[72] = Vs + (cur ^ 1) * 64;
      *(uint4*)&Kn[sr][sds] = kp;
      union { uint4 q; u16 e[8]; } tv;
      tv.q = SAME ? kp : vp;
#pragma unroll
      for (int j = 0; j < 8; ++j) Vn[sds + j][vcol] = tv.e[j];
      mcur[0] = mnxt[0];
      mcur[1] = mnxt[1];
      __syncthreads();
    }
  }
}

// ---------------- fused modulate+main attention ----------------
// One block = (b, h, 256 q-rows): 2 passes x 8 waves x 16 rows. Grid
// (2,16,16) = 512 blocks. LDS 36.9 KB.
// ROUND-7 LESSON: with LDS 36.9KB the backend's occupancy heuristic
// targeted 4 blocks/CU (8 waves/SIMD) and budgeted VGPR=64 -> ~48MB of
// loop spills (WRITE_SIZE 64.5MB). amdgpu_waves_per_eu(4,4) pins EXACTLY
// 4 waves/SIMD -> VGPR budget 128 -> the ~110-reg demand fits, no spill;
// 2 blocks/CU resident (VGPR-bound; LDS would allow 4).
__global__ __launch_bounds__(512)
__attribute__((amdgpu_waves_per_eu(4, 4))) void attn_fused(
    const u16* __restrict__ Qp, const u16* __restrict__ Pbp,
    const u16* __restrict__ Kp, const u16* __restrict__ Vp,
    const u64* __restrict__ B0, const u64* __restrict__ B1,
    u16* __restrict__ Op) {
  __shared__ u16 Ks[128][72];  // [0:64) buf0, [64:128) buf1
  __shared__ u16 Vs[128][72];
  const int tid = threadIdx.x;
  const int wave = tid >> 6, lane = tid & 63;
  const int quad = lane >> 4, l16 = lane & 15;
  const int qt = blockIdx.x, h = blockIdx.y, b = blockIdx.z;
  const int q0 = qt * 256;
  const long bs = (long)SL * HS;
  const u16* Qb = Qp + (long)b * bs + h * HD;
  const u16* Pb = Pbp + (long)b * bs + h * HD;
  const u16* Kb = Kp + (long)b * bs + h * HD;
  const u16* Vb = Vp + (long)b * bs + h * HD;
  const u64* M0 = B0 + (long)b * SL * 8;
  const u64* M1 = B1 + (long)b * SL * 8;
  const int sr = tid >> 3, sds = (tid & 7) * 8;
  const int vcol = sr ^ (((sds >> 4) & 3) << 4);
  const int qrow0 = q0 + wave * 16 + l16;  // pass p -> q-row qrow0 + p*128

  // Q A-frags -> registers (2 passes)
  short8 qf[2][2];
#pragma unroll
  for (int p = 0; p < 2; ++p)
#pragma unroll
    for (int kt = 0; kt < 2; ++kt)
      qf[p][kt] = *(const short8*)(Qb + (long)(qrow0 + p * 128) * HS +
                                   kt * 32 + quad * 8);

  float l_p[2] = {0.f, 0.f};
  f32x4 o[2][4];
#pragma unroll
  for (int p = 0; p < 2; ++p)
#pragma unroll
    for (int nt = 0; nt < 4; ++nt) o[p][nt] = (f32x4){0.f, 0.f, 0.f, 0.f};

  // ---- stage 1: modulate over img_abs (K = V = pb) ----
  attn_stage<true>(Pb, Pb, M0, qrow0, qf, l_p, o, Ks, Vs, quad, l16, sr, sds,
                   vcol);

  // ---- qm = Q + O/l per pass: O (C-layout) -> LDS -> A-layout, add Q ----
  __syncthreads();  // stage-1 tile-7 frag reads done before Ks overwrite
#pragma unroll
  for (int p = 0; p < 2; ++p) {
    float rs = l_p[p];
    rs += __shfl_xor(rs, 16, 64);
    rs += __shfl_xor(rs, 32, 64);
    float inv = 1.f / rs;  // row-sum^-1 for q-row qrow0 + p*128
    float invq[4];
#pragma unroll
    for (int i = 0; i < 4; ++i) invq[i] = __shfl(inv, quad * 4 + i, 64);
#pragma unroll
    for (int i = 0; i < 4; ++i)
#pragma unroll
      for (int nt = 0; nt < 4; ++nt)
        Ks[wave * 16 + quad * 4 + i][nt * 16 + l16] =
            f2bf(o[p][nt][i] * invq[i]);
    // wave-private rows: in-order LDS + compiler lgkmcnt; no barrier
#pragma unroll
    for (int kt = 0; kt < 2; ++kt) {
      short8 t8 = *(const short8*)&Ks[wave * 16 + l16][kt * 32 + quad * 8];
#pragma unroll
      for (int j = 0; j < 8; ++j)
        qf[p][kt][j] = (short)f2bf(bf2f((u16)t8[j]) + bf2f((u16)qf[p][kt][j]));
    }
#pragma unroll
    for (int nt = 0; nt < 4; ++nt) o[p][nt] = (f32x4){0.f, 0.f, 0.f, 0.f};
    l_p[p] = 0.f;
  }
  __syncthreads();  // rebuild reads done before stage-2 prologue writes

  // ---- stage 2: main attention over kh/vh ----
  attn_stage<false>(Kb, Vb, M1, qrow0, qf, l_p, o, Ks, Vs, quad, l16, sr, sds,
                    vcol);

  // ---- epilogue ----
  u16* Ob = Op + (long)b * bs + h * HD;
#pragma unroll
  for (int p = 0; p < 2; ++p) {
    float rs = l_p[p];
    rs += __shfl_xor(rs, 16, 64);
    rs += __shfl_xor(rs, 32, 64);
    float inv = 1.f / rs;
    float invq[4];
#pragma unroll
    for (int i = 0; i < 4; ++i) invq[i] = __shfl(inv, quad * 4 + i, 64);
#pragma unroll
    for (int i = 0; i < 4; ++i) {
      int r = q0 + p * 128 + wave * 16 + quad * 4 + i;
#pragma unroll
      for (int nt = 0; nt < 4; ++nt)
        Ob[(long)r * HS + nt * 16 + l16] = f2bf(o[p][nt][i] * invq[i]);
    }
  }
}

extern "C" void kernel_launch(void* const* d_in, const int* in_sizes, int n_in,
                              void* d_out, int out_size, void* d_ws,
                              size_t ws_size, hipStream_t stream) {
  const float* v   = (const float*)d_in[0];
  const float* k   = (const float*)d_in[1];
  const float* q   = (const float*)d_in[2];
  const float* img = (const float*)d_in[3];
  const float* Wv  = (const float*)d_in[4];
  const float* Wk  = (const float*)d_in[5];
  const float* Wq  = (const float*)d_in[6];
  const float* Wm  = (const float*)d_in[7];
  const int* absm  = (const int*)d_in[8];
  const int* mask  = (const int*)d_in[9];
  float* out = (float*)d_out;

  const long NTOK = NTOKC;
  const long NW   = NWC;
  const long NM   = NMC;
  // d_out (33.5 MB) doubles as bf16 staging for v,k; consumed by gemm_p3
  // before gemm_f overwrites it.
  u16* ovk = (u16*)d_out;
  u16* ws  = (u16*)d_ws;
  u16* xq  = ws;              // q bf16 staging; att output after attn_fused
  u16* pb  = ws + 1 * NTOK;   // img_abs bf16
  u16* vh  = ws + 2 * NTOK;   // gemm_p3 C base (vh,kh,qh contiguous)
  u16* kh  = ws + 3 * NTOK;
  u16* qh  = ws + 4 * NTOK;
  u16* w4  = ws + 5 * NTOK;
  u64* bt0 = (u64*)(w4 + 4 * NW);
  u64* bt1 = bt0 + NM / 64;
  u16* att = xq;

  prep<<<dim3(8192, 6), 256, 0, stream>>>(v, k, q, img, Wv, Wk, Wq, Wm,
                                          absm, mask, ovk, xq, pb, w4, bt0);
  gemm_p3<<<dim3(192, 8), 256, 0, stream>>>(ovk, xq, w4, vh);
  attn_fused<<<dim3(SL / 256, NHEAD, NB), 512, 0, stream>>>(
      qh, pb, kh, vh, bt0, bt1, att);
  gemm_f<<<dim3(NB * SL / 128, HS / 128), 256, 0, stream>>>(att, w4 + 3 * NW,
                                                            out);
}